// Round 6
// baseline (181.786 us; speedup 1.0000x reference)
//
#include <hip/hip_runtime.h>

// KANStressPredictor v12: v11 with typedef-shadowing fix.
// v11 failed to COMPILE: kernel-local variable `nf4` (num float4s) shadowed
// the global `typedef ... nf4` vector type inside the lambda. Rename the
// type to f32x4. No semantic change. v10's MLP theory still untested:
// v9 post-mortem: correct, VALU 50.6->20.4%, conflicts 0, but dur 61.4->59.2us.
// Three structures (v6/v7/v9) all land 59-62us with NO pipe saturated (VALU
// 20%, HBM 32%, LDS ~13%): ~65% of CU cycles are wave-wait -> latency/MLP-
// bound, not a BW wall (fillBuffer does 403MB @ 6.8TB/s in same harness).
// v10/v12 levers:
//  - prefetch depth 2 (two reg sets, 2-phase loop): ~6KB/wave outstanding,
//    loads issued 2 iterations before use (~2x slack vs ~900cy HBM latency).
//  - 1024 blocks x 8 chunks (4 blocks/CU, 16 waves/CU, 96KB/CU in flight;
//    Little's law needs ~9KB/CU at 6.3TB/s).
//  - fences 3->2: stage-write/linear-read recycle is lane-local -> per-thread
//    dep the compiler must preserve; only the 2 cross-lane transposes fence.
//  - nontemporal stores: output never re-read; keep L2/L3 for the input.
// Structure (from v8/v9): lane owns 3 consecutive float4 = exactly 4 triplets
// (768-float4 chunk triplet-aligned): 1.33 compute3/float4, no shuffles.
// Per-WAVE 3KB LDS slab, zero s_barrier. log2(lam1)=log2(det)-log2(lam0):
// 5 trans/triplet. Memory floor: 201.3MB -> ~32us @ 6.3TB/s.
// NOTE: __builtin_log2f/exp2f, NOT __log2f/__exp2f (glibc host-pass collision).

typedef unsigned int u32;
typedef float f32x4 __attribute__((ext_vector_type(4)));  // native vec for nt-store

// Wave-level LDS fence: compiler barrier + wait for DS ops to commit.
// Does NOT wait on vmcnt -> global prefetch stays in flight across it.
#define WAVE_LDS_FENCE() asm volatile("s_waitcnt lgkmcnt(0)" ::: "memory")

__device__ __forceinline__ void compute3(float s0, float s1, float s2,
                                         float ki0, float ki1,
                                         float& o0, float& o1, float& o2) {
    const float c00 = __builtin_fmaf(2.0f, s0, 1.0f);
    const float c11 = __builtin_fmaf(2.0f, s1, 1.0f);
    const float c01 = s2;
    const float det = c00 * c11 - c01 * c01;          // det(C) > 0 (SPD)
    const float l2det = __builtin_log2f(det);
    const float mean = 0.5f * (c00 + c11);
    const float diff = 0.5f * (c00 - c11);
    const float rad  = __builtin_sqrtf(__builtin_fmaf(diff, diff, c01 * c01));
    const float l2lam0 = __builtin_log2f(mean - rad); // no cancellation: mean>=1
    const float l2a = -0.16666666667f * l2det;        // log2(det^(-1/6))
    o0 = __builtin_exp2f(ki0 * __builtin_fmaf(0.5f, l2lam0, l2a));
    // log2(lam1) = l2det - l2lam0
    o1 = __builtin_exp2f(ki0 * __builtin_fmaf(-0.5f, l2lam0,
                                  __builtin_fmaf(0.5f, l2det, l2a)));
    o2 = (0.34657359028f * l2det) * ki1;              // log(J)=0.5*ln2*l2det
}

constexpr int TPB = 256;
constexpr int WPB = TPB / 64;          // 4 waves/block
constexpr int WCH = 192;               // float4 per wave-chunk (256 triplets)
constexpr int BCH = WPB * WCH;         // 768 float4 per block-chunk (1024 triplets)

__global__ __launch_bounds__(TPB) void kan_v12_mlp(
    const float* __restrict__ strain,
    const float* __restrict__ ki0p,
    const float* __restrict__ ki1p,
    float* __restrict__ out,
    int nfloat_i)
{
    __shared__ float4 slab[WPB][WCH];  // 12,288 B/block
    const float ki0 = ki0p[0];
    const float ki1 = ki1p[0];
    const u32 nfloat = (u32)nfloat_i;
    const u32 nquads = nfloat >> 2;
    const u32 nchunk = nquads / BCH;
    const u32 t = threadIdx.x;
    const u32 w = t >> 6;
    const u32 l = t & 63u;
    float4* S = slab[w];               // wave-private slab
    const float4* __restrict__ in4 = (const float4*)strain;
    float4* __restrict__ out4 = (float4*)out;
    const u32 G = gridDim.x;

    // process one staged chunk; issues the depth-2 prefetch into (r0,r1,r2)
    auto do_chunk = [&](u32 cc, float4& r0, float4& r1, float4& r2) {
        // stage (linear, conflict-free). WAR vs previous linear reads is
        // lane-local (same addresses) -> ordered per-thread, no fence.
        S[l] = r0; S[l + 64] = r1; S[l + 128] = r2;

        const u32 cf = cc + 2u * G;    // depth-2 prefetch
        if (cf < nchunk) {
            const float4* p = in4 + (size_t)cf * BCH + (size_t)w * WCH;
            r0 = p[l]; r1 = p[l + 64]; r2 = p[l + 128];
        }

        WAVE_LDS_FENCE();  // cross-lane: stage writes -> strided reads

        const float4 x = S[3u * l];
        const float4 y = S[3u * l + 1];
        const float4 z = S[3u * l + 2];

        float o0,o1,o2,o3,o4,o5,o6,o7,o8,o9,oa,ob;
        compute3(x.x, x.y, x.z, ki0, ki1, o0, o1, o2);
        compute3(x.w, y.x, y.y, ki0, ki1, o3, o4, o5);
        compute3(y.z, y.w, z.x, ki0, ki1, o6, o7, o8);
        compute3(z.y, z.z, z.w, ki0, ki1, o9, oa, ob);

        S[3u * l]     = make_float4(o0, o1, o2, o3);
        S[3u * l + 1] = make_float4(o4, o5, o6, o7);
        S[3u * l + 2] = make_float4(o8, o9, oa, ob);

        WAVE_LDS_FENCE();  // cross-lane: strided writes -> linear reads

        f32x4* d = (f32x4*)(out4 + (size_t)cc * BCH + (size_t)w * WCH);
        __builtin_nontemporal_store(*(const f32x4*)&S[l],       d + l);
        __builtin_nontemporal_store(*(const f32x4*)&S[l + 64],  d + l + 64);
        __builtin_nontemporal_store(*(const f32x4*)&S[l + 128], d + l + 128);
    };

    u32 c = blockIdx.x;
    float4 a0, a1, a2, b0, b1, b2;
    if (c < nchunk) {                   // prologue: 2 chunks in flight
        const float4* p = in4 + (size_t)c * BCH + (size_t)w * WCH;
        a0 = p[l]; a1 = p[l + 64]; a2 = p[l + 128];
    }
    if (c + G < nchunk) {
        const float4* p = in4 + (size_t)(c + G) * BCH + (size_t)w * WCH;
        b0 = p[l]; b1 = p[l + 64]; b2 = p[l + 128];
    }
    while (c < nchunk) {
        do_chunk(c, a0, a1, a2);
        const u32 cb = c + G;
        if (cb < nchunk) do_chunk(cb, b0, b1, b2);
        c += 2u * G;
    }

    // tail: triplets past the last full chunk (empty for the bench shape)
    const u32 ntrip = nfloat / 3u;
    const u32 t0 = nchunk * (BCH * 4u / 3u);   // 1024 triplets per chunk
    const u32 gs = G * (u32)TPB;
    for (u32 e = t0 + blockIdx.x * (u32)TPB + t; e < ntrip; e += gs) {
        float x0, x1, x2;
        compute3(strain[3 * e], strain[3 * e + 1], strain[3 * e + 2],
                 ki0, ki1, x0, x1, x2);
        out[3 * e]     = x0;
        out[3 * e + 1] = x1;
        out[3 * e + 2] = x2;
    }
}

extern "C" void kernel_launch(void* const* d_in, const int* in_sizes, int n_in,
                              void* d_out, int out_size, void* d_ws, size_t ws_size,
                              hipStream_t stream) {
    const float* strain = (const float*)d_in[0];
    const float* ki0p   = (const float*)d_in[1];
    const float* ki1p   = (const float*)d_in[2];
    float* out = (float*)d_out;

    const int nfloat = in_sizes[0];
    const u32 nquads = ((u32)nfloat) >> 2;
    const u32 nchunk = nquads / (u32)BCH;
    u32 blocks = nchunk / 8u;              // 8 chunks per block
    if (blocks > 1024u) blocks = 1024u;    // 4 blocks/CU, 16 waves/CU
    if (blocks < 1u) blocks = 1u;

    kan_v12_mlp<<<(int)blocks, TPB, 0, stream>>>(strain, ki0p, ki1p, out, nfloat);
}